// Round 18
// baseline (1940.936 us; speedup 1.0000x reference)
//
#include <hip/hip_runtime.h>
#include <algorithm>

#define FIN 24
#define NHID 64
#define NMIX 216
#define NOUT 6
#define BN_EPS 1e-5f
#define SROW 148  // LDS row stride (floats): 16B-aligned, even bank spread

// ---------- CSR build ----------
__global__ void k_hist(const int* __restrict__ ei, int E, int* deg) {
    int e = blockIdx.x * blockDim.x + threadIdx.x;
    if (e < E) atomicAdd(&deg[ei[E + e]], 1);
}

// block-local exclusive scan over deg (n+1 elements); also emits dis = 1/sqrt(deg)
__global__ void k_scan_local(const int* __restrict__ deg, int n, int* rowptr, int* bsum,
                             float* __restrict__ dis) {
    __shared__ int s[256];
    int i = blockIdx.x * 256 + threadIdx.x;
    int v = (i < n) ? deg[i] : 0;
    if (i < n) dis[i] = v > 0 ? rsqrtf((float)v) : 0.f;
    s[threadIdx.x] = v;
    __syncthreads();
#pragma unroll
    for (int off = 1; off < 256; off <<= 1) {
        int x = (threadIdx.x >= off) ? s[threadIdx.x - off] : 0;
        __syncthreads();
        s[threadIdx.x] += x;
        __syncthreads();
    }
    if (i <= n) rowptr[i] = s[threadIdx.x] - v;  // exclusive
    if (threadIdx.x == 255) bsum[blockIdx.x] = s[255];
}

__global__ void k_scan_bsum(int* bsum, int nb) {
    __shared__ int s[256];
    int carry = 0;
    for (int base = 0; base < nb; base += 256) {
        int i = base + threadIdx.x;
        int v = (i < nb) ? bsum[i] : 0;
        s[threadIdx.x] = v;
        __syncthreads();
#pragma unroll
        for (int off = 1; off < 256; off <<= 1) {
            int x = (threadIdx.x >= off) ? s[threadIdx.x - off] : 0;
            __syncthreads();
            s[threadIdx.x] += x;
            __syncthreads();
        }
        if (i < nb) bsum[i] = s[threadIdx.x] - v + carry;
        carry += s[255];
        __syncthreads();
    }
}

__global__ void k_scan_add(int* rowptr, const int* __restrict__ bsum, int n) {
    int i = blockIdx.x * 256 + threadIdx.x;
    if (i <= n) rowptr[i] += bsum[blockIdx.x];
}

// fill CSR with packed (col, val) per edge
__global__ void k_fill(const int* __restrict__ ei, int E, const float* __restrict__ dis,
                       const int* __restrict__ rowptr, int* fill, int2* __restrict__ cv) {
    int e = blockIdx.x * blockDim.x + threadIdx.x;
    if (e >= E) return;
    int s = ei[e], d = ei[E + e];
    int slot = rowptr[d] + atomicAdd(&fill[d], 1);
    cv[slot] = make_int2(s, __float_as_int(-dis[s] * dis[d]));
}

// transpose 3 Cheb weight sets: W [6][24][64] -> Wt [6][64][24]
__global__ void k_wt3(const float* __restrict__ Wa, float* __restrict__ Ta,
                      const float* __restrict__ Wb, float* __restrict__ Tb,
                      const float* __restrict__ Wc, float* __restrict__ Tc) {
    int o = blockIdx.x * blockDim.x + threadIdx.x;  // 0 .. 3*9216-1
    int which = o / 9216, oo = o - which * 9216;
    const float* W = (which == 0) ? Wa : (which == 1) ? Wb : Wc;
    float* T       = (which == 0) ? Ta : (which == 1) ? Tb : Tc;
    int k = oo / 1536, r = oo - k * 1536;
    int j = r / FIN, f = r - j * FIN;
    T[oo] = W[k * 1536 + f * NHID + j];
}

// ---------- gather prop, thread per (dst node, float4 chunk), 4-deep MLP ----------
__global__ void k_propg(const int* __restrict__ rowptr, const int2* __restrict__ cv,
                        float scale, const float* __restrict__ h,
                        const float* __restrict__ prev, float* __restrict__ out, int n) {
    int idx = blockIdx.x * blockDim.x + threadIdx.x;
    if (idx >= n * 6) return;
    int d = idx / 6, q = idx - d * 6;
    int beg = rowptr[d], end = rowptr[d + 1];
    const float4* h4 = reinterpret_cast<const float4*>(h);
    float ax = 0.f, ay = 0.f, az = 0.f, aw = 0.f;
    float bx = 0.f, by = 0.f, bz = 0.f, bw = 0.f;
    float cx = 0.f, cy = 0.f, cz = 0.f, cw = 0.f;
    float dx = 0.f, dy = 0.f, dz = 0.f, dw = 0.f;
    int e = beg;
    for (; e + 4 <= end; e += 4) {
        int2 c0 = cv[e], c1 = cv[e + 1], c2 = cv[e + 2], c3 = cv[e + 3];
        float w0 = __int_as_float(c0.y), w1 = __int_as_float(c1.y);
        float w2 = __int_as_float(c2.y), w3 = __int_as_float(c3.y);
        float4 h0 = h4[(size_t)c0.x * 6 + q];
        float4 h1 = h4[(size_t)c1.x * 6 + q];
        float4 h2 = h4[(size_t)c2.x * 6 + q];
        float4 h3 = h4[(size_t)c3.x * 6 + q];
        ax = fmaf(w0, h0.x, ax); ay = fmaf(w0, h0.y, ay);
        az = fmaf(w0, h0.z, az); aw = fmaf(w0, h0.w, aw);
        bx = fmaf(w1, h1.x, bx); by = fmaf(w1, h1.y, by);
        bz = fmaf(w1, h1.z, bz); bw = fmaf(w1, h1.w, bw);
        cx = fmaf(w2, h2.x, cx); cy = fmaf(w2, h2.y, cy);
        cz = fmaf(w2, h2.z, cz); cw = fmaf(w2, h2.w, cw);
        dx = fmaf(w3, h3.x, dx); dy = fmaf(w3, h3.y, dy);
        dz = fmaf(w3, h3.z, dz); dw = fmaf(w3, h3.w, dw);
    }
    for (; e + 2 <= end; e += 2) {
        int2 c0 = cv[e], c1 = cv[e + 1];
        float w0 = __int_as_float(c0.y), w1 = __int_as_float(c1.y);
        float4 h0 = h4[(size_t)c0.x * 6 + q];
        float4 h1 = h4[(size_t)c1.x * 6 + q];
        ax = fmaf(w0, h0.x, ax); ay = fmaf(w0, h0.y, ay);
        az = fmaf(w0, h0.z, az); aw = fmaf(w0, h0.w, aw);
        bx = fmaf(w1, h1.x, bx); by = fmaf(w1, h1.y, by);
        bz = fmaf(w1, h1.z, bz); bw = fmaf(w1, h1.w, bw);
    }
    if (e < end) {
        int2 c0 = cv[e];
        float w0 = __int_as_float(c0.y);
        float4 h0 = h4[(size_t)c0.x * 6 + q];
        ax = fmaf(w0, h0.x, ax); ay = fmaf(w0, h0.y, ay);
        az = fmaf(w0, h0.z, az); aw = fmaf(w0, h0.w, aw);
    }
    ax += bx + cx + dx; ay += by + cy + dy;
    az += bz + cz + dz; aw += bw + cw + dw;
    float4 r;
    if (prev) {
        float4 pv = reinterpret_cast<const float4*>(prev)[idx];
        r = make_float4(fmaf(scale, ax, -pv.x), fmaf(scale, ay, -pv.y),
                        fmaf(scale, az, -pv.z), fmaf(scale, aw, -pv.w));
    } else {
        r = make_float4(scale * ax, scale * ay, scale * az, scale * aw);
    }
    reinterpret_cast<float4*>(out)[idx] = r;
}

// ---------- 6-term gemv: 64 nodes/block, lane = node, wave = j-group ----------
// All 6 S rows per node staged ONCE in LDS ([64][SROW], unique-row ds_reads);
// thread (node = tid&63, jg = tid>>6) keeps av[16]; W columns wave-uniform ->
// scalar pipe. Single S read (no amplification), no spill, no broadcasts.
__global__ void k_gemv6(const float* __restrict__ S0, const float* __restrict__ S1,
                        const float* __restrict__ S2, const float* __restrict__ S3,
                        const float* __restrict__ S4, const float* __restrict__ S5,
                        const float* __restrict__ Wt, const float* __restrict__ bias,
                        float* __restrict__ acc, float* __restrict__ stats, int n) {
    __shared__ float sb[64 * SROW];  // 37.9 KB
    int tid = threadIdx.x;
    int nbase = blockIdx.x * 64;
    // ---- stage: 2304 float4 (6 mats x 64 nodes x 6 chunks); 9 per thread ----
#pragma unroll
    for (int it = 0; it < 9; ++it) {
        int idx = it * 256 + tid;            // 0..2303
        int k = idx / 384;                   // matrix
        int r = idx - k * 384;               // 0..383
        int nd = r / 6, q = r - nd * 6;
        int node = nbase + nd;
        const float* Sk = (k == 0) ? S0 : (k == 1) ? S1 : (k == 2) ? S2
                        : (k == 3) ? S3 : (k == 4) ? S4 : S5;
        float4 v = (node < n)
            ? *reinterpret_cast<const float4*>(Sk + (size_t)node * FIN + q * 4)
            : make_float4(0.f, 0.f, 0.f, 0.f);
        *reinterpret_cast<float4*>(&sb[nd * SROW + k * FIN + q * 4]) = v;
    }
    __syncthreads();
    int l = tid & 63;        // node lane
    int jg = tid >> 6;       // j-group 0..3 (wave-uniform)
    int node = nbase + l;
    bool ok = (node < n);
    const float* rowb = &sb[l * SROW];
    float av[16];
#pragma unroll
    for (int jj = 0; jj < 16; ++jj) av[jj] = bias[jg * 16 + jj];  // uniform
#pragma unroll 1
    for (int k = 0; k < 6; ++k) {
        const float4* r4 = reinterpret_cast<const float4*>(rowb + k * FIN);
        float4 v0 = r4[0], v1 = r4[1], v2 = r4[2], v3 = r4[3], v4 = r4[4], v5 = r4[5];
        const float* Wk = Wt + k * (NHID * FIN) + (jg * 16) * FIN;
#pragma unroll
        for (int jj = 0; jj < 16; ++jj) {
            const float* ww = Wk + jj * FIN;  // uniform -> s_load
            float a = av[jj];
            a = fmaf(v0.x, ww[0], a);  a = fmaf(v0.y, ww[1], a);
            a = fmaf(v0.z, ww[2], a);  a = fmaf(v0.w, ww[3], a);
            a = fmaf(v1.x, ww[4], a);  a = fmaf(v1.y, ww[5], a);
            a = fmaf(v1.z, ww[6], a);  a = fmaf(v1.w, ww[7], a);
            a = fmaf(v2.x, ww[8], a);  a = fmaf(v2.y, ww[9], a);
            a = fmaf(v2.z, ww[10], a); a = fmaf(v2.w, ww[11], a);
            a = fmaf(v3.x, ww[12], a); a = fmaf(v3.y, ww[13], a);
            a = fmaf(v3.z, ww[14], a); a = fmaf(v3.w, ww[15], a);
            a = fmaf(v4.x, ww[16], a); a = fmaf(v4.y, ww[17], a);
            a = fmaf(v4.z, ww[18], a); a = fmaf(v4.w, ww[19], a);
            a = fmaf(v5.x, ww[20], a); a = fmaf(v5.y, ww[21], a);
            a = fmaf(v5.z, ww[22], a); a = fmaf(v5.w, ww[23], a);
            av[jj] = a;
        }
    }
    if (!ok) {
#pragma unroll
        for (int jj = 0; jj < 16; ++jj) av[jj] = 0.f;  // exclude from stats
    }
    // ---- store: each lane owns one 64B j-segment of its node's acc row ----
    if (ok) {
        float* op = acc + (size_t)node * NHID + jg * 16;
#pragma unroll
        for (int s4 = 0; s4 < 4; ++s4)
            reinterpret_cast<float4*>(op)[s4] =
                make_float4(av[s4 * 4 + 0], av[s4 * 4 + 1], av[s4 * 4 + 2], av[s4 * 4 + 3]);
    }
    // ---- stats: butterfly over 64 node-lanes per j ----
#pragma unroll
    for (int jj = 0; jj < 16; ++jj) {
        float s = av[jj], q = av[jj] * av[jj];
#pragma unroll
        for (int d = 32; d; d >>= 1) {
            s += __shfl_xor(s, d, 64);
            q += __shfl_xor(q, d, 64);
        }
        if (l == 0) {
            atomicAdd(&stats[jg * 16 + jj], s);
            atomicAdd(&stats[NHID + jg * 16 + jj], q);
        }
    }
}

// BN coefficients for all 3 branches: scX[0:64]=scale, scX[64:128]=shift
__global__ void k_bnprep3(const float* __restrict__ st1, const float* __restrict__ g1,
                          const float* __restrict__ bt1, float inv1,
                          const float* __restrict__ st2, const float* __restrict__ g2,
                          const float* __restrict__ bt2, float inv2,
                          const float* __restrict__ st3, const float* __restrict__ g3,
                          const float* __restrict__ bt3, float inv3,
                          float* __restrict__ s1, float* __restrict__ s2,
                          float* __restrict__ s3) {
    int b = threadIdx.x >> 6, i = threadIdx.x & 63;
    const float* st = (b == 0) ? st1 : (b == 1) ? st2 : st3;
    const float* g  = (b == 0) ? g1  : (b == 1) ? g2  : g3;
    const float* bt = (b == 0) ? bt1 : (b == 1) ? bt2 : bt3;
    float inv       = (b == 0) ? inv1 : (b == 1) ? inv2 : inv3;
    float* so       = (b == 0) ? s1  : (b == 1) ? s2  : s3;
    float m = st[i] * inv;
    float v = st[NHID + i] * inv - m * m;
    float sc = g[i] * rsqrtf(v + BN_EPS);
    so[i] = sc;
    so[NHID + i] = fmaf(-m, sc, bt[i]);
}

// fused segment-mean scatter for both clusterings (reads x once)
__global__ void k_scatter2(const float* __restrict__ x, const int* __restrict__ cl1,
                           const int* __restrict__ cl2, int n,
                           float* xp1, float* cnt1, float* xp2, float* cnt2) {
    int idx = blockIdx.x * blockDim.x + threadIdx.x;
    if (idx >= n * FIN) return;
    int node = idx / FIN, f = idx - node * FIN;
    float v = x[idx];
    int c1 = cl1[node], c2 = cl2[node];
    atomicAdd(&xp1[c1 * FIN + f], v);
    atomicAdd(&xp2[c2 * FIN + f], v);
    if (f == 0) { atomicAdd(&cnt1[c1], 1.f); atomicAdd(&cnt2[c2], 1.f); }
}

__global__ void k_divcnt(float* xp, const float* __restrict__ cnt, int c) {
    int idx = blockIdx.x * blockDim.x + threadIdx.x;
    if (idx >= c * FIN) return;
    xp[idx] = xp[idx] / fmaxf(cnt[idx / FIN], 1.f);
}

// fused mix: thread per node; BN+ReLU for all three branches via precomputed
// scale/shift (uniform scalar loads); Wm/bm scalar-indexed.
__global__ void k_final(const float* __restrict__ acc1, const float* __restrict__ sc1,
                        const float* __restrict__ h2, const float* __restrict__ sc2,
                        const int* __restrict__ cl1,
                        const float* __restrict__ h3, const float* __restrict__ sc3,
                        const int* __restrict__ cl2,
                        const float* __restrict__ x, const float* __restrict__ Wm,
                        const float* __restrict__ bm, float* __restrict__ out, int n) {
    int t = blockIdx.x * blockDim.x + threadIdx.x;
    if (t >= n) return;
    float o[NOUT];
#pragma unroll
    for (int j = 0; j < NOUT; ++j) o[j] = bm[j];
    {
        const float4* r4 = reinterpret_cast<const float4*>(acc1 + (size_t)t * NHID);
#pragma unroll
        for (int i4 = 0; i4 < NHID / 4; ++i4) {
            float4 v = r4[i4];
            float hv[4] = {v.x, v.y, v.z, v.w};
#pragma unroll
            for (int c = 0; c < 4; ++c) {
                int i = i4 * 4 + c;
                float h = fmaxf(fmaf(hv[c], sc1[i], sc1[NHID + i]), 0.f);
#pragma unroll
                for (int j = 0; j < NOUT; ++j) o[j] = fmaf(h, Wm[i * NOUT + j], o[j]);
            }
        }
    }
    {
        const float4* r4 = reinterpret_cast<const float4*>(h2 + (size_t)cl1[t] * NHID);
#pragma unroll
        for (int i4 = 0; i4 < NHID / 4; ++i4) {
            float4 v = r4[i4];
            float hv[4] = {v.x, v.y, v.z, v.w};
#pragma unroll
            for (int c = 0; c < 4; ++c) {
                int hid = i4 * 4 + c;
                float h = fmaxf(fmaf(hv[c], sc2[hid], sc2[NHID + hid]), 0.f);
#pragma unroll
                for (int j = 0; j < NOUT; ++j) o[j] = fmaf(h, Wm[(NHID + hid) * NOUT + j], o[j]);
            }
        }
    }
    {
        const float4* r4 = reinterpret_cast<const float4*>(h3 + (size_t)cl2[t] * NHID);
#pragma unroll
        for (int i4 = 0; i4 < NHID / 4; ++i4) {
            float4 v = r4[i4];
            float hv[4] = {v.x, v.y, v.z, v.w};
#pragma unroll
            for (int c = 0; c < 4; ++c) {
                int hid = i4 * 4 + c;
                float h = fmaxf(fmaf(hv[c], sc3[hid], sc3[NHID + hid]), 0.f);
#pragma unroll
                for (int j = 0; j < NOUT; ++j) o[j] = fmaf(h, Wm[(2 * NHID + hid) * NOUT + j], o[j]);
            }
        }
    }
    {
        const float4* r4 = reinterpret_cast<const float4*>(x + (size_t)t * FIN);
#pragma unroll
        for (int i4 = 0; i4 < FIN / 4; ++i4) {
            float4 v = r4[i4];
            float hv[4] = {v.x, v.y, v.z, v.w};
#pragma unroll
            for (int c = 0; c < 4; ++c) {
                int i = 3 * NHID + i4 * 4 + c;
#pragma unroll
                for (int j = 0; j < NOUT; ++j) o[j] = fmaf(hv[c], Wm[i * NOUT + j], o[j]);
            }
        }
    }
    float* op = out + (size_t)t * NOUT;
#pragma unroll
    for (int j = 0; j < NOUT; ++j) op[j] = o[j];
}

extern "C" void kernel_launch(void* const* d_in, const int* in_sizes, int n_in,
                              void* d_out, int out_size, void* d_ws, size_t ws_size,
                              hipStream_t stream) {
    const int N = 200000, E = 800000;
    const int C1n = 20000, E1 = 80000;
    const int C2n = 2000, E2 = 8000;

    const float* x  = (const float*)d_in[0];
    const int* ei   = (const int*)d_in[1];
    const int* cl1  = (const int*)d_in[2];
    const int* cl2  = (const int*)d_in[3];
    const int* eic1 = (const int*)d_in[4];
    const int* eic2 = (const int*)d_in[5];
    const float* W1 = (const float*)d_in[6];  const float* b1 = (const float*)d_in[7];
    const float* g1 = (const float*)d_in[8];  const float* bt1 = (const float*)d_in[9];
    const float* W2 = (const float*)d_in[10]; const float* b2 = (const float*)d_in[11];
    const float* g2 = (const float*)d_in[12]; const float* bt2 = (const float*)d_in[13];
    const float* W3 = (const float*)d_in[14]; const float* b3 = (const float*)d_in[15];
    const float* g3 = (const float*)d_in[16]; const float* bt3 = (const float*)d_in[17];
    const float* Wm = (const float*)d_in[18]; const float* bm = (const float*)d_in[19];

    char* wb = (char*)d_ws;
    size_t off = 0;
    auto alloc = [&](size_t nwords) {
        void* p = wb + off; off += ((nwords + 3) & ~(size_t)3) * 4; return p;
    };
    // --- zero-region ---
    int* degi1 = (int*)alloc(N);   int* fill1 = (int*)alloc(N);
    int* degi2 = (int*)alloc(C1n); int* fill2 = (int*)alloc(C1n);
    int* degi3 = (int*)alloc(C2n); int* fill3 = (int*)alloc(C2n);
    float* st1 = (float*)alloc(128); float* st2 = (float*)alloc(128); float* st3 = (float*)alloc(128);
    float* xp1 = (float*)alloc((size_t)C1n * FIN); float* cnt1 = (float*)alloc(C1n);
    float* xp2 = (float*)alloc((size_t)C2n * FIN); float* cnt2 = (float*)alloc(C2n);
    size_t zero_bytes = off;
    // --- fully-overwritten region ---
    int* rp1 = (int*)alloc(N + 1);   int2* cv1 = (int2*)alloc(2 * (size_t)E);
    int* rp2 = (int*)alloc(C1n + 1); int2* cv2 = (int2*)alloc(2 * (size_t)E1);
    int* rp3 = (int*)alloc(C2n + 1); int2* cv3 = (int2*)alloc(2 * (size_t)E2);
    float* dis1 = (float*)alloc(N); float* dis2 = (float*)alloc(C1n); float* dis3 = (float*)alloc(C2n);
    int* bsum = (int*)alloc(1024);
    float* scsh1 = (float*)alloc(128); float* scsh2 = (float*)alloc(128); float* scsh3 = (float*)alloc(128);
    float* Wt1 = (float*)alloc(9216); float* Wt2 = (float*)alloc(9216); float* Wt3 = (float*)alloc(9216);
    float* T1[5]; for (int i = 0; i < 5; ++i) T1[i] = (float*)alloc((size_t)N * FIN);
    float* T2[5]; for (int i = 0; i < 5; ++i) T2[i] = (float*)alloc((size_t)C1n * FIN);
    float* T3[5]; for (int i = 0; i < 5; ++i) T3[i] = (float*)alloc((size_t)C2n * FIN);
    float* acc1 = (float*)alloc((size_t)N * NHID);
    float* acc2 = (float*)alloc((size_t)C1n * NHID);
    float* acc3 = (float*)alloc((size_t)C2n * NHID);
    if (off > ws_size) return;  // fail visibly if ws too small

    (void)hipMemsetAsync(d_ws, 0, zero_bytes, stream);

    const int T = 256;
    auto cdiv = [](int a, int b) { return (a + b - 1) / b; };

    // transpose all Cheb weights up front (independent of everything else)
    k_wt3<<<cdiv(3 * 9216, T), T, 0, stream>>>(W1, Wt1, W2, Wt2, W3, Wt3);

    auto branch = [&](const float* xin, int n, const int* e, int Ecnt,
                      const float* Wt, const float* bb, int* degi, int* fill, float* dis,
                      int* rp, int2* cv, float** Tb, float* acc, float* st) {
        int ge = cdiv(Ecnt, T);
        int nb = cdiv(n + 1, 256);
        int gg = cdiv(n, 64);        // gemv6: 64 nodes per block
        int gp = cdiv(n * 6, T);     // propg: thread per (node, chunk)
        // CSR build
        k_hist<<<ge, T, 0, stream>>>(e, Ecnt, degi);
        k_scan_local<<<nb, 256, 0, stream>>>(degi, n, rp, bsum, dis);
        k_scan_bsum<<<1, 256, 0, stream>>>(bsum, nb);
        k_scan_add<<<nb, 256, 0, stream>>>(rp, bsum, n);
        k_fill<<<ge, T, 0, stream>>>(e, Ecnt, dis, rp, fill, cv);
        // Chebyshev chain: Tb[0]=Tx1 .. Tb[4]=Tx5
        k_propg<<<gp, T, 0, stream>>>(rp, cv, 1.0f, xin, nullptr, Tb[0], n);
        k_propg<<<gp, T, 0, stream>>>(rp, cv, 2.0f, Tb[0], xin, Tb[1], n);
        k_propg<<<gp, T, 0, stream>>>(rp, cv, 2.0f, Tb[1], Tb[0], Tb[2], n);
        k_propg<<<gp, T, 0, stream>>>(rp, cv, 2.0f, Tb[2], Tb[1], Tb[3], n);
        k_propg<<<gp, T, 0, stream>>>(rp, cv, 2.0f, Tb[3], Tb[2], Tb[4], n);
        // single-pass 6-term gemv (+BN stats)
        k_gemv6<<<gg, T, 0, stream>>>(xin, Tb[0], Tb[1], Tb[2], Tb[3], Tb[4],
                                      Wt, bb, acc, st, n);
    };

    // branch 1: full graph
    branch(x, N, ei, E, Wt1, b1, degi1, fill1, dis1, rp1, cv1, T1, acc1, st1);
    // pooled inputs for branches 2 & 3 (single pass over x)
    k_scatter2<<<cdiv(N * FIN, T), T, 0, stream>>>(x, cl1, cl2, N, xp1, cnt1, xp2, cnt2);
    k_divcnt<<<cdiv(C1n * FIN, T), T, 0, stream>>>(xp1, cnt1, C1n);
    branch(xp1, C1n, eic1, E1, Wt2, b2, degi2, fill2, dis2, rp2, cv2, T2, acc2, st2);
    k_divcnt<<<cdiv(C2n * FIN, T), T, 0, stream>>>(xp2, cnt2, C2n);
    branch(xp2, C2n, eic2, E2, Wt3, b3, degi3, fill3, dis3, rp3, cv3, T3, acc3, st3);
    // BN coefficients for all three branches, then fused final mix
    k_bnprep3<<<1, 192, 0, stream>>>(st1, g1, bt1, 1.0f / (float)N,
                                     st2, g2, bt2, 1.0f / (float)C1n,
                                     st3, g3, bt3, 1.0f / (float)C2n,
                                     scsh1, scsh2, scsh3);
    k_final<<<cdiv(N, T), T, 0, stream>>>(acc1, scsh1, acc2, scsh2, cl1,
                                          acc3, scsh3, cl2,
                                          x, Wm, bm, (float*)d_out, N);
}

// Round 19
// 1906.216 us; speedup vs baseline: 1.0182x; 1.0182x over previous
//
#include <hip/hip_runtime.h>
#include <algorithm>

#define FIN 24
#define NHID 64
#define NMIX 216
#define NOUT 6
#define BN_EPS 1e-5f
#define SROW 148  // LDS row stride (floats), 16B-aligned

// ---------- CSR build ----------
__global__ void k_hist(const int* __restrict__ ei, int E, int* deg) {
    int e = blockIdx.x * blockDim.x + threadIdx.x;
    if (e < E) atomicAdd(&deg[ei[E + e]], 1);
}

// block-local exclusive scan over deg (n+1 elements); also emits dis = 1/sqrt(deg)
__global__ void k_scan_local(const int* __restrict__ deg, int n, int* rowptr, int* bsum,
                             float* __restrict__ dis) {
    __shared__ int s[256];
    int i = blockIdx.x * 256 + threadIdx.x;
    int v = (i < n) ? deg[i] : 0;
    if (i < n) dis[i] = v > 0 ? rsqrtf((float)v) : 0.f;
    s[threadIdx.x] = v;
    __syncthreads();
#pragma unroll
    for (int off = 1; off < 256; off <<= 1) {
        int x = (threadIdx.x >= off) ? s[threadIdx.x - off] : 0;
        __syncthreads();
        s[threadIdx.x] += x;
        __syncthreads();
    }
    if (i <= n) rowptr[i] = s[threadIdx.x] - v;  // exclusive
    if (threadIdx.x == 255) bsum[blockIdx.x] = s[255];
}

__global__ void k_scan_bsum(int* bsum, int nb) {
    __shared__ int s[256];
    int carry = 0;
    for (int base = 0; base < nb; base += 256) {
        int i = base + threadIdx.x;
        int v = (i < nb) ? bsum[i] : 0;
        s[threadIdx.x] = v;
        __syncthreads();
#pragma unroll
        for (int off = 1; off < 256; off <<= 1) {
            int x = (threadIdx.x >= off) ? s[threadIdx.x - off] : 0;
            __syncthreads();
            s[threadIdx.x] += x;
            __syncthreads();
        }
        if (i < nb) bsum[i] = s[threadIdx.x] - v + carry;
        carry += s[255];
        __syncthreads();
    }
}

__global__ void k_scan_add(int* rowptr, const int* __restrict__ bsum, int n) {
    int i = blockIdx.x * 256 + threadIdx.x;
    if (i <= n) rowptr[i] += bsum[blockIdx.x];
}

// fill CSR with packed (col, val) per edge
__global__ void k_fill(const int* __restrict__ ei, int E, const float* __restrict__ dis,
                       const int* __restrict__ rowptr, int* fill, int2* __restrict__ cv) {
    int e = blockIdx.x * blockDim.x + threadIdx.x;
    if (e >= E) return;
    int s = ei[e], d = ei[E + e];
    int slot = rowptr[d] + atomicAdd(&fill[d], 1);
    cv[slot] = make_int2(s, __float_as_int(-dis[s] * dis[d]));
}

// transpose 3 Cheb weight sets: W [6][24][64] -> Wt [6][64][24]
__global__ void k_wt3(const float* __restrict__ Wa, float* __restrict__ Ta,
                      const float* __restrict__ Wb, float* __restrict__ Tb,
                      const float* __restrict__ Wc, float* __restrict__ Tc) {
    int o = blockIdx.x * blockDim.x + threadIdx.x;  // 0 .. 3*9216-1
    int which = o / 9216, oo = o - which * 9216;
    const float* W = (which == 0) ? Wa : (which == 1) ? Wb : Wc;
    float* T       = (which == 0) ? Ta : (which == 1) ? Tb : Tc;
    int k = oo / 1536, r = oo - k * 1536;
    int j = r / FIN, f = r - j * FIN;
    T[oo] = W[k * 1536 + f * NHID + j];
}

// ---------- gather prop, thread per (dst node, float4 chunk), 4-deep MLP ----------
__global__ void k_propg(const int* __restrict__ rowptr, const int2* __restrict__ cv,
                        float scale, const float* __restrict__ h,
                        const float* __restrict__ prev, float* __restrict__ out, int n) {
    int idx = blockIdx.x * blockDim.x + threadIdx.x;
    if (idx >= n * 6) return;
    int d = idx / 6, q = idx - d * 6;
    int beg = rowptr[d], end = rowptr[d + 1];
    const float4* h4 = reinterpret_cast<const float4*>(h);
    float ax = 0.f, ay = 0.f, az = 0.f, aw = 0.f;
    float bx = 0.f, by = 0.f, bz = 0.f, bw = 0.f;
    float cx = 0.f, cy = 0.f, cz = 0.f, cw = 0.f;
    float dx = 0.f, dy = 0.f, dz = 0.f, dw = 0.f;
    int e = beg;
    for (; e + 4 <= end; e += 4) {
        int2 c0 = cv[e], c1 = cv[e + 1], c2 = cv[e + 2], c3 = cv[e + 3];
        float w0 = __int_as_float(c0.y), w1 = __int_as_float(c1.y);
        float w2 = __int_as_float(c2.y), w3 = __int_as_float(c3.y);
        float4 h0 = h4[(size_t)c0.x * 6 + q];
        float4 h1 = h4[(size_t)c1.x * 6 + q];
        float4 h2 = h4[(size_t)c2.x * 6 + q];
        float4 h3 = h4[(size_t)c3.x * 6 + q];
        ax = fmaf(w0, h0.x, ax); ay = fmaf(w0, h0.y, ay);
        az = fmaf(w0, h0.z, az); aw = fmaf(w0, h0.w, aw);
        bx = fmaf(w1, h1.x, bx); by = fmaf(w1, h1.y, by);
        bz = fmaf(w1, h1.z, bz); bw = fmaf(w1, h1.w, bw);
        cx = fmaf(w2, h2.x, cx); cy = fmaf(w2, h2.y, cy);
        cz = fmaf(w2, h2.z, cz); cw = fmaf(w2, h2.w, cw);
        dx = fmaf(w3, h3.x, dx); dy = fmaf(w3, h3.y, dy);
        dz = fmaf(w3, h3.z, dz); dw = fmaf(w3, h3.w, dw);
    }
    for (; e + 2 <= end; e += 2) {
        int2 c0 = cv[e], c1 = cv[e + 1];
        float w0 = __int_as_float(c0.y), w1 = __int_as_float(c1.y);
        float4 h0 = h4[(size_t)c0.x * 6 + q];
        float4 h1 = h4[(size_t)c1.x * 6 + q];
        ax = fmaf(w0, h0.x, ax); ay = fmaf(w0, h0.y, ay);
        az = fmaf(w0, h0.z, az); aw = fmaf(w0, h0.w, aw);
        bx = fmaf(w1, h1.x, bx); by = fmaf(w1, h1.y, by);
        bz = fmaf(w1, h1.z, bz); bw = fmaf(w1, h1.w, bw);
    }
    if (e < end) {
        int2 c0 = cv[e];
        float w0 = __int_as_float(c0.y);
        float4 h0 = h4[(size_t)c0.x * 6 + q];
        ax = fmaf(w0, h0.x, ax); ay = fmaf(w0, h0.y, ay);
        az = fmaf(w0, h0.z, az); aw = fmaf(w0, h0.w, aw);
    }
    ax += bx + cx + dx; ay += by + cy + dy;
    az += bz + cz + dz; aw += bw + cw + dw;
    float4 r;
    if (prev) {
        float4 pv = reinterpret_cast<const float4*>(prev)[idx];
        r = make_float4(fmaf(scale, ax, -pv.x), fmaf(scale, ay, -pv.y),
                        fmaf(scale, az, -pv.z), fmaf(scale, aw, -pv.w));
    } else {
        r = make_float4(scale * ax, scale * ay, scale * az, scale * aw);
    }
    reinterpret_cast<float4*>(out)[idx] = r;
}

// ---------- 6-term gemv: 64 nodes/block, lane = node, wave = j-group ----------
// S rows staged ONCE in LDS (unique-row ds_reads); av[16] per thread; W via
// scalar pipe — jg forced wave-uniform with readfirstlane so the compiler
// emits s_load for W (R18's regression was jg=tid>>6 -> vector W loads).
__global__ void k_gemv6(const float* __restrict__ S0, const float* __restrict__ S1,
                        const float* __restrict__ S2, const float* __restrict__ S3,
                        const float* __restrict__ S4, const float* __restrict__ S5,
                        const float* __restrict__ Wt, const float* __restrict__ bias,
                        float* __restrict__ acc, float* __restrict__ stats, int n) {
    __shared__ float sb[64 * SROW];  // 37.9 KB
    int tid = threadIdx.x;
    int nbase = blockIdx.x * 64;
    // ---- stage: 2304 float4 (6 mats x 64 nodes x 6 chunks); 9 per thread ----
#pragma unroll
    for (int it = 0; it < 9; ++it) {
        int idx = it * 256 + tid;            // 0..2303
        int k = idx / 384;                   // matrix
        int r = idx - k * 384;               // 0..383
        int nd = r / 6, q = r - nd * 6;
        int node = nbase + nd;
        const float* Sk = (k == 0) ? S0 : (k == 1) ? S1 : (k == 2) ? S2
                        : (k == 3) ? S3 : (k == 4) ? S4 : S5;
        float4 v = (node < n)
            ? *reinterpret_cast<const float4*>(Sk + (size_t)node * FIN + q * 4)
            : make_float4(0.f, 0.f, 0.f, 0.f);
        *reinterpret_cast<float4*>(&sb[nd * SROW + k * FIN + q * 4]) = v;
    }
    __syncthreads();
    int l = tid & 63;                                          // node lane
    int jg = __builtin_amdgcn_readfirstlane(tid >> 6);         // j-group, UNIFORM
    int node = nbase + l;
    bool ok = (node < n);
    const float* rowb = &sb[l * SROW];
    float av[16];
#pragma unroll
    for (int jj = 0; jj < 16; ++jj) av[jj] = bias[jg * 16 + jj];  // uniform
#pragma unroll 1
    for (int k = 0; k < 6; ++k) {
        const float4* r4 = reinterpret_cast<const float4*>(rowb + k * FIN);
        float4 v0 = r4[0], v1 = r4[1], v2 = r4[2], v3 = r4[3], v4 = r4[4], v5 = r4[5];
        const float* Wk = Wt + k * (NHID * FIN) + (jg * 16) * FIN;
#pragma unroll
        for (int jj = 0; jj < 16; ++jj) {
            const float* ww = Wk + jj * FIN;  // uniform -> s_load
            float a = av[jj];
            a = fmaf(v0.x, ww[0], a);  a = fmaf(v0.y, ww[1], a);
            a = fmaf(v0.z, ww[2], a);  a = fmaf(v0.w, ww[3], a);
            a = fmaf(v1.x, ww[4], a);  a = fmaf(v1.y, ww[5], a);
            a = fmaf(v1.z, ww[6], a);  a = fmaf(v1.w, ww[7], a);
            a = fmaf(v2.x, ww[8], a);  a = fmaf(v2.y, ww[9], a);
            a = fmaf(v2.z, ww[10], a); a = fmaf(v2.w, ww[11], a);
            a = fmaf(v3.x, ww[12], a); a = fmaf(v3.y, ww[13], a);
            a = fmaf(v3.z, ww[14], a); a = fmaf(v3.w, ww[15], a);
            a = fmaf(v4.x, ww[16], a); a = fmaf(v4.y, ww[17], a);
            a = fmaf(v4.z, ww[18], a); a = fmaf(v4.w, ww[19], a);
            a = fmaf(v5.x, ww[20], a); a = fmaf(v5.y, ww[21], a);
            a = fmaf(v5.z, ww[22], a); a = fmaf(v5.w, ww[23], a);
            av[jj] = a;
        }
    }
    if (!ok) {
#pragma unroll
        for (int jj = 0; jj < 16; ++jj) av[jj] = 0.f;  // exclude from stats
    }
    // ---- store: each lane owns one 64B j-segment of its node's acc row ----
    if (ok) {
        float* op = acc + (size_t)node * NHID + jg * 16;
#pragma unroll
        for (int s4 = 0; s4 < 4; ++s4)
            reinterpret_cast<float4*>(op)[s4] =
                make_float4(av[s4 * 4 + 0], av[s4 * 4 + 1], av[s4 * 4 + 2], av[s4 * 4 + 3]);
    }
    // ---- stats: butterfly over 64 node-lanes per j ----
#pragma unroll
    for (int jj = 0; jj < 16; ++jj) {
        float s = av[jj], q = av[jj] * av[jj];
#pragma unroll
        for (int d = 32; d; d >>= 1) {
            s += __shfl_xor(s, d, 64);
            q += __shfl_xor(q, d, 64);
        }
        if (l == 0) {
            atomicAdd(&stats[jg * 16 + jj], s);
            atomicAdd(&stats[NHID + jg * 16 + jj], q);
        }
    }
}

// BN coefficients for all 3 branches: scX[0:64]=scale, scX[64:128]=shift
__global__ void k_bnprep3(const float* __restrict__ st1, const float* __restrict__ g1,
                          const float* __restrict__ bt1, float inv1,
                          const float* __restrict__ st2, const float* __restrict__ g2,
                          const float* __restrict__ bt2, float inv2,
                          const float* __restrict__ st3, const float* __restrict__ g3,
                          const float* __restrict__ bt3, float inv3,
                          float* __restrict__ s1, float* __restrict__ s2,
                          float* __restrict__ s3) {
    int b = threadIdx.x >> 6, i = threadIdx.x & 63;
    const float* st = (b == 0) ? st1 : (b == 1) ? st2 : st3;
    const float* g  = (b == 0) ? g1  : (b == 1) ? g2  : g3;
    const float* bt = (b == 0) ? bt1 : (b == 1) ? bt2 : bt3;
    float inv       = (b == 0) ? inv1 : (b == 1) ? inv2 : inv3;
    float* so       = (b == 0) ? s1  : (b == 1) ? s2  : s3;
    float m = st[i] * inv;
    float v = st[NHID + i] * inv - m * m;
    float sc = g[i] * rsqrtf(v + BN_EPS);
    so[i] = sc;
    so[NHID + i] = fmaf(-m, sc, bt[i]);
}

// fused segment-mean scatter for both clusterings (reads x once)
__global__ void k_scatter2(const float* __restrict__ x, const int* __restrict__ cl1,
                           const int* __restrict__ cl2, int n,
                           float* xp1, float* cnt1, float* xp2, float* cnt2) {
    int idx = blockIdx.x * blockDim.x + threadIdx.x;
    if (idx >= n * FIN) return;
    int node = idx / FIN, f = idx - node * FIN;
    float v = x[idx];
    int c1 = cl1[node], c2 = cl2[node];
    atomicAdd(&xp1[c1 * FIN + f], v);
    atomicAdd(&xp2[c2 * FIN + f], v);
    if (f == 0) { atomicAdd(&cnt1[c1], 1.f); atomicAdd(&cnt2[c2], 1.f); }
}

__global__ void k_divcnt(float* xp, const float* __restrict__ cnt, int c) {
    int idx = blockIdx.x * blockDim.x + threadIdx.x;
    if (idx >= c * FIN) return;
    xp[idx] = xp[idx] / fmaxf(cnt[idx / FIN], 1.f);
}

// fused mix: thread per node; BN+ReLU for all three branches via precomputed
// scale/shift (uniform scalar loads); Wm/bm scalar-indexed.
__global__ void k_final(const float* __restrict__ acc1, const float* __restrict__ sc1,
                        const float* __restrict__ h2, const float* __restrict__ sc2,
                        const int* __restrict__ cl1,
                        const float* __restrict__ h3, const float* __restrict__ sc3,
                        const int* __restrict__ cl2,
                        const float* __restrict__ x, const float* __restrict__ Wm,
                        const float* __restrict__ bm, float* __restrict__ out, int n) {
    int t = blockIdx.x * blockDim.x + threadIdx.x;
    if (t >= n) return;
    float o[NOUT];
#pragma unroll
    for (int j = 0; j < NOUT; ++j) o[j] = bm[j];
    {
        const float4* r4 = reinterpret_cast<const float4*>(acc1 + (size_t)t * NHID);
#pragma unroll
        for (int i4 = 0; i4 < NHID / 4; ++i4) {
            float4 v = r4[i4];
            float hv[4] = {v.x, v.y, v.z, v.w};
#pragma unroll
            for (int c = 0; c < 4; ++c) {
                int i = i4 * 4 + c;
                float h = fmaxf(fmaf(hv[c], sc1[i], sc1[NHID + i]), 0.f);
#pragma unroll
                for (int j = 0; j < NOUT; ++j) o[j] = fmaf(h, Wm[i * NOUT + j], o[j]);
            }
        }
    }
    {
        const float4* r4 = reinterpret_cast<const float4*>(h2 + (size_t)cl1[t] * NHID);
#pragma unroll
        for (int i4 = 0; i4 < NHID / 4; ++i4) {
            float4 v = r4[i4];
            float hv[4] = {v.x, v.y, v.z, v.w};
#pragma unroll
            for (int c = 0; c < 4; ++c) {
                int hid = i4 * 4 + c;
                float h = fmaxf(fmaf(hv[c], sc2[hid], sc2[NHID + hid]), 0.f);
#pragma unroll
                for (int j = 0; j < NOUT; ++j) o[j] = fmaf(h, Wm[(NHID + hid) * NOUT + j], o[j]);
            }
        }
    }
    {
        const float4* r4 = reinterpret_cast<const float4*>(h3 + (size_t)cl2[t] * NHID);
#pragma unroll
        for (int i4 = 0; i4 < NHID / 4; ++i4) {
            float4 v = r4[i4];
            float hv[4] = {v.x, v.y, v.z, v.w};
#pragma unroll
            for (int c = 0; c < 4; ++c) {
                int hid = i4 * 4 + c;
                float h = fmaxf(fmaf(hv[c], sc3[hid], sc3[NHID + hid]), 0.f);
#pragma unroll
                for (int j = 0; j < NOUT; ++j) o[j] = fmaf(h, Wm[(2 * NHID + hid) * NOUT + j], o[j]);
            }
        }
    }
    {
        const float4* r4 = reinterpret_cast<const float4*>(x + (size_t)t * FIN);
#pragma unroll
        for (int i4 = 0; i4 < FIN / 4; ++i4) {
            float4 v = r4[i4];
            float hv[4] = {v.x, v.y, v.z, v.w};
#pragma unroll
            for (int c = 0; c < 4; ++c) {
                int i = 3 * NHID + i4 * 4 + c;
#pragma unroll
                for (int j = 0; j < NOUT; ++j) o[j] = fmaf(hv[c], Wm[i * NOUT + j], o[j]);
            }
        }
    }
    float* op = out + (size_t)t * NOUT;
#pragma unroll
    for (int j = 0; j < NOUT; ++j) op[j] = o[j];
}

extern "C" void kernel_launch(void* const* d_in, const int* in_sizes, int n_in,
                              void* d_out, int out_size, void* d_ws, size_t ws_size,
                              hipStream_t stream) {
    const int N = 200000, E = 800000;
    const int C1n = 20000, E1 = 80000;
    const int C2n = 2000, E2 = 8000;

    const float* x  = (const float*)d_in[0];
    const int* ei   = (const int*)d_in[1];
    const int* cl1  = (const int*)d_in[2];
    const int* cl2  = (const int*)d_in[3];
    const int* eic1 = (const int*)d_in[4];
    const int* eic2 = (const int*)d_in[5];
    const float* W1 = (const float*)d_in[6];  const float* b1 = (const float*)d_in[7];
    const float* g1 = (const float*)d_in[8];  const float* bt1 = (const float*)d_in[9];
    const float* W2 = (const float*)d_in[10]; const float* b2 = (const float*)d_in[11];
    const float* g2 = (const float*)d_in[12]; const float* bt2 = (const float*)d_in[13];
    const float* W3 = (const float*)d_in[14]; const float* b3 = (const float*)d_in[15];
    const float* g3 = (const float*)d_in[16]; const float* bt3 = (const float*)d_in[17];
    const float* Wm = (const float*)d_in[18]; const float* bm = (const float*)d_in[19];

    char* wb = (char*)d_ws;
    size_t off = 0;
    auto alloc = [&](size_t nwords) {
        void* p = wb + off; off += ((nwords + 3) & ~(size_t)3) * 4; return p;
    };
    // --- zero-region ---
    int* degi1 = (int*)alloc(N);   int* fill1 = (int*)alloc(N);
    int* degi2 = (int*)alloc(C1n); int* fill2 = (int*)alloc(C1n);
    int* degi3 = (int*)alloc(C2n); int* fill3 = (int*)alloc(C2n);
    float* st1 = (float*)alloc(128); float* st2 = (float*)alloc(128); float* st3 = (float*)alloc(128);
    float* xp1 = (float*)alloc((size_t)C1n * FIN); float* cnt1 = (float*)alloc(C1n);
    float* xp2 = (float*)alloc((size_t)C2n * FIN); float* cnt2 = (float*)alloc(C2n);
    size_t zero_bytes = off;
    // --- fully-overwritten region ---
    int* rp1 = (int*)alloc(N + 1);   int2* cv1 = (int2*)alloc(2 * (size_t)E);
    int* rp2 = (int*)alloc(C1n + 1); int2* cv2 = (int2*)alloc(2 * (size_t)E1);
    int* rp3 = (int*)alloc(C2n + 1); int2* cv3 = (int2*)alloc(2 * (size_t)E2);
    float* dis1 = (float*)alloc(N); float* dis2 = (float*)alloc(C1n); float* dis3 = (float*)alloc(C2n);
    int* bsum = (int*)alloc(1024);
    float* scsh1 = (float*)alloc(128); float* scsh2 = (float*)alloc(128); float* scsh3 = (float*)alloc(128);
    float* Wt1 = (float*)alloc(9216); float* Wt2 = (float*)alloc(9216); float* Wt3 = (float*)alloc(9216);
    float* T1[5]; for (int i = 0; i < 5; ++i) T1[i] = (float*)alloc((size_t)N * FIN);
    float* T2[5]; for (int i = 0; i < 5; ++i) T2[i] = (float*)alloc((size_t)C1n * FIN);
    float* T3[5]; for (int i = 0; i < 5; ++i) T3[i] = (float*)alloc((size_t)C2n * FIN);
    float* acc1 = (float*)alloc((size_t)N * NHID);
    float* acc2 = (float*)alloc((size_t)C1n * NHID);
    float* acc3 = (float*)alloc((size_t)C2n * NHID);
    if (off > ws_size) return;  // fail visibly if ws too small

    (void)hipMemsetAsync(d_ws, 0, zero_bytes, stream);

    const int T = 256;
    auto cdiv = [](int a, int b) { return (a + b - 1) / b; };

    // transpose all Cheb weights up front (independent of everything else)
    k_wt3<<<cdiv(3 * 9216, T), T, 0, stream>>>(W1, Wt1, W2, Wt2, W3, Wt3);

    auto branch = [&](const float* xin, int n, const int* e, int Ecnt,
                      const float* Wt, const float* bb, int* degi, int* fill, float* dis,
                      int* rp, int2* cv, float** Tb, float* acc, float* st) {
        int ge = cdiv(Ecnt, T);
        int nb = cdiv(n + 1, 256);
        int gg = cdiv(n, 64);        // gemv6: 64 nodes per block
        int gp = cdiv(n * 6, T);     // propg: thread per (node, chunk)
        // CSR build
        k_hist<<<ge, T, 0, stream>>>(e, Ecnt, degi);
        k_scan_local<<<nb, 256, 0, stream>>>(degi, n, rp, bsum, dis);
        k_scan_bsum<<<1, 256, 0, stream>>>(bsum, nb);
        k_scan_add<<<nb, 256, 0, stream>>>(rp, bsum, n);
        k_fill<<<ge, T, 0, stream>>>(e, Ecnt, dis, rp, fill, cv);
        // Chebyshev chain: Tb[0]=Tx1 .. Tb[4]=Tx5
        k_propg<<<gp, T, 0, stream>>>(rp, cv, 1.0f, xin, nullptr, Tb[0], n);
        k_propg<<<gp, T, 0, stream>>>(rp, cv, 2.0f, Tb[0], xin, Tb[1], n);
        k_propg<<<gp, T, 0, stream>>>(rp, cv, 2.0f, Tb[1], Tb[0], Tb[2], n);
        k_propg<<<gp, T, 0, stream>>>(rp, cv, 2.0f, Tb[2], Tb[1], Tb[3], n);
        k_propg<<<gp, T, 0, stream>>>(rp, cv, 2.0f, Tb[3], Tb[2], Tb[4], n);
        // single-pass 6-term gemv (+BN stats)
        k_gemv6<<<gg, T, 0, stream>>>(xin, Tb[0], Tb[1], Tb[2], Tb[3], Tb[4],
                                      Wt, bb, acc, st, n);
    };

    // branch 1: full graph
    branch(x, N, ei, E, Wt1, b1, degi1, fill1, dis1, rp1, cv1, T1, acc1, st1);
    // pooled inputs for branches 2 & 3 (single pass over x)
    k_scatter2<<<cdiv(N * FIN, T), T, 0, stream>>>(x, cl1, cl2, N, xp1, cnt1, xp2, cnt2);
    k_divcnt<<<cdiv(C1n * FIN, T), T, 0, stream>>>(xp1, cnt1, C1n);
    branch(xp1, C1n, eic1, E1, Wt2, b2, degi2, fill2, dis2, rp2, cv2, T2, acc2, st2);
    k_divcnt<<<cdiv(C2n * FIN, T), T, 0, stream>>>(xp2, cnt2, C2n);
    branch(xp2, C2n, eic2, E2, Wt3, b3, degi3, fill3, dis3, rp3, cv3, T3, acc3, st3);
    // BN coefficients for all three branches, then fused final mix
    k_bnprep3<<<1, 192, 0, stream>>>(st1, g1, bt1, 1.0f / (float)N,
                                     st2, g2, bt2, 1.0f / (float)C1n,
                                     st3, g3, bt3, 1.0f / (float)C2n,
                                     scsh1, scsh2, scsh3);
    k_final<<<cdiv(N, T), T, 0, stream>>>(acc1, scsh1, acc2, scsh2, cl1,
                                          acc3, scsh3, cl2,
                                          x, Wm, bm, (float*)d_out, N);
}

// Round 21
// 640.343 us; speedup vs baseline: 3.0311x; 2.9769x over previous
//
#include <hip/hip_runtime.h>
#include <algorithm>

#define FIN 24
#define NHID 64
#define NMIX 216
#define NOUT 6
#define BN_EPS 1e-5f

// ---------- CSR build ----------
__global__ void k_hist(const int* __restrict__ ei, int E, int* deg) {
    int e = blockIdx.x * blockDim.x + threadIdx.x;
    if (e < E) atomicAdd(&deg[ei[E + e]], 1);
}

// block-local exclusive scan over deg (n+1 elements); also emits dis = 1/sqrt(deg)
__global__ void k_scan_local(const int* __restrict__ deg, int n, int* rowptr, int* bsum,
                             float* __restrict__ dis) {
    __shared__ int s[256];
    int i = blockIdx.x * 256 + threadIdx.x;
    int v = (i < n) ? deg[i] : 0;
    if (i < n) dis[i] = v > 0 ? rsqrtf((float)v) : 0.f;
    s[threadIdx.x] = v;
    __syncthreads();
#pragma unroll
    for (int off = 1; off < 256; off <<= 1) {
        int x = (threadIdx.x >= off) ? s[threadIdx.x - off] : 0;
        __syncthreads();
        s[threadIdx.x] += x;
        __syncthreads();
    }
    if (i <= n) rowptr[i] = s[threadIdx.x] - v;  // exclusive
    if (threadIdx.x == 255) bsum[blockIdx.x] = s[255];
}

__global__ void k_scan_bsum(int* bsum, int nb) {
    __shared__ int s[256];
    int carry = 0;
    for (int base = 0; base < nb; base += 256) {
        int i = base + threadIdx.x;
        int v = (i < nb) ? bsum[i] : 0;
        s[threadIdx.x] = v;
        __syncthreads();
#pragma unroll
        for (int off = 1; off < 256; off <<= 1) {
            int x = (threadIdx.x >= off) ? s[threadIdx.x - off] : 0;
            __syncthreads();
            s[threadIdx.x] += x;
            __syncthreads();
        }
        if (i < nb) bsum[i] = s[threadIdx.x] - v + carry;
        carry += s[255];
        __syncthreads();
    }
}

__global__ void k_scan_add(int* rowptr, const int* __restrict__ bsum, int n) {
    int i = blockIdx.x * 256 + threadIdx.x;
    if (i <= n) rowptr[i] += bsum[blockIdx.x];
}

// fill CSR with packed (col, val) per edge
__global__ void k_fill(const int* __restrict__ ei, int E, const float* __restrict__ dis,
                       const int* __restrict__ rowptr, int* fill, int2* __restrict__ cv) {
    int e = blockIdx.x * blockDim.x + threadIdx.x;
    if (e >= E) return;
    int s = ei[e], d = ei[E + e];
    int slot = rowptr[d] + atomicAdd(&fill[d], 1);
    cv[slot] = make_int2(s, __float_as_int(-dis[s] * dis[d]));
}

// transpose 3 Cheb weight sets: W [6][24][64] -> Wt [6][64][24]
__global__ void k_wt3(const float* __restrict__ Wa, float* __restrict__ Ta,
                      const float* __restrict__ Wb, float* __restrict__ Tb,
                      const float* __restrict__ Wc, float* __restrict__ Tc) {
    int o = blockIdx.x * blockDim.x + threadIdx.x;  // 0 .. 3*9216-1
    int which = o / 9216, oo = o - which * 9216;
    const float* W = (which == 0) ? Wa : (which == 1) ? Wb : Wc;
    float* T       = (which == 0) ? Ta : (which == 1) ? Tb : Tc;
    int k = oo / 1536, r = oo - k * 1536;
    int j = r / FIN, f = r - j * FIN;
    T[oo] = W[k * 1536 + f * NHID + j];
}

// ---------- gather prop, thread per (dst node, float4 chunk), 4-deep MLP ----------
__global__ void k_propg(const int* __restrict__ rowptr, const int2* __restrict__ cv,
                        float scale, const float* __restrict__ h,
                        const float* __restrict__ prev, float* __restrict__ out, int n) {
    int idx = blockIdx.x * blockDim.x + threadIdx.x;
    if (idx >= n * 6) return;
    int d = idx / 6, q = idx - d * 6;
    int beg = rowptr[d], end = rowptr[d + 1];
    const float4* h4 = reinterpret_cast<const float4*>(h);
    float ax = 0.f, ay = 0.f, az = 0.f, aw = 0.f;
    float bx = 0.f, by = 0.f, bz = 0.f, bw = 0.f;
    float cx = 0.f, cy = 0.f, cz = 0.f, cw = 0.f;
    float dx = 0.f, dy = 0.f, dz = 0.f, dw = 0.f;
    int e = beg;
    for (; e + 4 <= end; e += 4) {
        int2 c0 = cv[e], c1 = cv[e + 1], c2 = cv[e + 2], c3 = cv[e + 3];
        float w0 = __int_as_float(c0.y), w1 = __int_as_float(c1.y);
        float w2 = __int_as_float(c2.y), w3 = __int_as_float(c3.y);
        float4 h0 = h4[(size_t)c0.x * 6 + q];
        float4 h1 = h4[(size_t)c1.x * 6 + q];
        float4 h2 = h4[(size_t)c2.x * 6 + q];
        float4 h3 = h4[(size_t)c3.x * 6 + q];
        ax = fmaf(w0, h0.x, ax); ay = fmaf(w0, h0.y, ay);
        az = fmaf(w0, h0.z, az); aw = fmaf(w0, h0.w, aw);
        bx = fmaf(w1, h1.x, bx); by = fmaf(w1, h1.y, by);
        bz = fmaf(w1, h1.z, bz); bw = fmaf(w1, h1.w, bw);
        cx = fmaf(w2, h2.x, cx); cy = fmaf(w2, h2.y, cy);
        cz = fmaf(w2, h2.z, cz); cw = fmaf(w2, h2.w, cw);
        dx = fmaf(w3, h3.x, dx); dy = fmaf(w3, h3.y, dy);
        dz = fmaf(w3, h3.z, dz); dw = fmaf(w3, h3.w, dw);
    }
    for (; e + 2 <= end; e += 2) {
        int2 c0 = cv[e], c1 = cv[e + 1];
        float w0 = __int_as_float(c0.y), w1 = __int_as_float(c1.y);
        float4 h0 = h4[(size_t)c0.x * 6 + q];
        float4 h1 = h4[(size_t)c1.x * 6 + q];
        ax = fmaf(w0, h0.x, ax); ay = fmaf(w0, h0.y, ay);
        az = fmaf(w0, h0.z, az); aw = fmaf(w0, h0.w, aw);
        bx = fmaf(w1, h1.x, bx); by = fmaf(w1, h1.y, by);
        bz = fmaf(w1, h1.z, bz); bw = fmaf(w1, h1.w, bw);
    }
    if (e < end) {
        int2 c0 = cv[e];
        float w0 = __int_as_float(c0.y);
        float4 h0 = h4[(size_t)c0.x * 6 + q];
        ax = fmaf(w0, h0.x, ax); ay = fmaf(w0, h0.y, ay);
        az = fmaf(w0, h0.z, az); aw = fmaf(w0, h0.w, aw);
    }
    ax += bx + cx + dx; ay += by + cy + dy;
    az += bz + cz + dz; aw += bw + cw + dw;
    float4 r;
    if (prev) {
        float4 pv = reinterpret_cast<const float4*>(prev)[idx];
        r = make_float4(fmaf(scale, ax, -pv.x), fmaf(scale, ay, -pv.y),
                        fmaf(scale, az, -pv.z), fmaf(scale, aw, -pv.w));
    } else {
        r = make_float4(scale * ax, scale * ay, scale * az, scale * aw);
    }
    reinterpret_cast<float4*>(out)[idx] = r;
}

// ---------- 6-term gemv, lane = node, j-chunk in grid, XCD-aware remap ----------
// R17 structure (av[16], 4 j-chunks in grid), with blockIdx remapped so the
// 4 chunk-blocks of one node tile share bid%8 -> same XCD -> chunk 0's S-row
// fetch warms the L2 that chunks 1-3 read. bid = ((t8*4 + c)<<3) | xcd.
__global__ void k_gemv6(const float* __restrict__ S0, const float* __restrict__ S1,
                        const float* __restrict__ S2, const float* __restrict__ S3,
                        const float* __restrict__ S4, const float* __restrict__ S5,
                        const float* __restrict__ Wt, const float* __restrict__ bias,
                        float* __restrict__ acc, float* __restrict__ stats, int n) {
    __shared__ float tile[4][64 * 17];  // per-wave transpose tile, 17.4 KB
    int l = threadIdx.x & 63;
    int w = threadIdx.x >> 6;
    int bid = blockIdx.x;
    int xcd = bid & 7;
    int grp = bid >> 3;
    int c = grp & 3;                        // j-chunk 0..3
    int tnum = (grp >> 2) * 8 + xcd;        // node tile
    int ntiles = (n + 255) >> 8;
    if (tnum >= ntiles) return;
    int nbase = tnum * 256 + w * 64;
    int node = nbase + l;
    bool ok = (node < n);
    int nodec = ok ? node : (n - 1);
    float* tl = &tile[w][0];
    float av[16];
#pragma unroll
    for (int jj = 0; jj < 16; ++jj) av[jj] = bias[c * 16 + jj];  // uniform
#pragma unroll 1
    for (int k = 0; k < 6; ++k) {
        const float* Sk = (k == 0) ? S0 : (k == 1) ? S1 : (k == 2) ? S2
                        : (k == 3) ? S3 : (k == 4) ? S4 : S5;
        const float4* r = reinterpret_cast<const float4*>(Sk + (size_t)nodec * FIN);
        float4 v0 = r[0], v1 = r[1], v2 = r[2], v3 = r[3], v4 = r[4], v5 = r[5];
        const float* Wk = Wt + k * (NHID * FIN) + (c * 16) * FIN;
#pragma unroll
        for (int jj = 0; jj < 16; ++jj) {
            const float* ww = Wk + jj * FIN;     // uniform -> s_load
            float a = av[jj];
            a = fmaf(v0.x, ww[0], a);  a = fmaf(v0.y, ww[1], a);
            a = fmaf(v0.z, ww[2], a);  a = fmaf(v0.w, ww[3], a);
            a = fmaf(v1.x, ww[4], a);  a = fmaf(v1.y, ww[5], a);
            a = fmaf(v1.z, ww[6], a);  a = fmaf(v1.w, ww[7], a);
            a = fmaf(v2.x, ww[8], a);  a = fmaf(v2.y, ww[9], a);
            a = fmaf(v2.z, ww[10], a); a = fmaf(v2.w, ww[11], a);
            a = fmaf(v3.x, ww[12], a); a = fmaf(v3.y, ww[13], a);
            a = fmaf(v3.z, ww[14], a); a = fmaf(v3.w, ww[15], a);
            a = fmaf(v4.x, ww[16], a); a = fmaf(v4.y, ww[17], a);
            a = fmaf(v4.z, ww[18], a); a = fmaf(v4.w, ww[19], a);
            a = fmaf(v5.x, ww[20], a); a = fmaf(v5.y, ww[21], a);
            a = fmaf(v5.z, ww[22], a); a = fmaf(v5.w, ww[23], a);
            av[jj] = a;
        }
    }
    if (!ok) {
#pragma unroll
        for (int jj = 0; jj < 16; ++jj) av[jj] = 0.f;  // exclude from stats
    }
    // ---- store + stats for this chunk via per-wave LDS transpose ----
#pragma unroll
    for (int jj = 0; jj < 16; ++jj) tl[l * 17 + jj] = av[jj];
    asm volatile("" ::: "memory");  // wave-lockstep write->read order
#pragma unroll
    for (int it = 0; it < 4; ++it) {
        int lin = it * 64 + l;
        int nd = lin >> 2, qj = lin & 3;
        int gnode = nbase + nd;
        if (gnode < n) {
            float4 vv = make_float4(tl[nd * 17 + qj * 4 + 0], tl[nd * 17 + qj * 4 + 1],
                                    tl[nd * 17 + qj * 4 + 2], tl[nd * 17 + qj * 4 + 3]);
            *reinterpret_cast<float4*>(acc + (size_t)gnode * NHID + c * 16 + qj * 4) = vv;
        }
    }
    // per-j stats partials: 4 lanes per j, each sums 16 nodes
    float ps = 0.f, pq = 0.f;
    int jj = l & 15, ndb = (l >> 4) * 16;
#pragma unroll
    for (int t = 0; t < 16; ++t) {
        float vv = tl[(ndb + t) * 17 + jj];
        ps += vv; pq = fmaf(vv, vv, pq);
    }
    ps += __shfl_xor(ps, 16, 64); pq += __shfl_xor(pq, 16, 64);
    ps += __shfl_xor(ps, 32, 64); pq += __shfl_xor(pq, 32, 64);
    if (l < 16) {
        atomicAdd(&stats[c * 16 + jj], ps);
        atomicAdd(&stats[NHID + c * 16 + jj], pq);
    }
}

// BN coefficients for all 3 branches: scX[0:64]=scale, scX[64:128]=shift
__global__ void k_bnprep3(const float* __restrict__ st1, const float* __restrict__ g1,
                          const float* __restrict__ bt1, float inv1,
                          const float* __restrict__ st2, const float* __restrict__ g2,
                          const float* __restrict__ bt2, float inv2,
                          const float* __restrict__ st3, const float* __restrict__ g3,
                          const float* __restrict__ bt3, float inv3,
                          float* __restrict__ s1, float* __restrict__ s2,
                          float* __restrict__ s3) {
    int b = threadIdx.x >> 6, i = threadIdx.x & 63;
    const float* st = (b == 0) ? st1 : (b == 1) ? st2 : st3;
    const float* g  = (b == 0) ? g1  : (b == 1) ? g2  : g3;
    const float* bt = (b == 0) ? bt1 : (b == 1) ? bt2 : bt3;
    float inv       = (b == 0) ? inv1 : (b == 1) ? inv2 : inv3;
    float* so       = (b == 0) ? s1  : (b == 1) ? s2  : s3;
    float m = st[i] * inv;
    float v = st[NHID + i] * inv - m * m;
    float sc = g[i] * rsqrtf(v + BN_EPS);
    so[i] = sc;
    so[NHID + i] = fmaf(-m, sc, bt[i]);
}

// fused segment-mean scatter for both clusterings (reads x once)
__global__ void k_scatter2(const float* __restrict__ x, const int* __restrict__ cl1,
                           const int* __restrict__ cl2, int n,
                           float* xp1, float* cnt1, float* xp2, float* cnt2) {
    int idx = blockIdx.x * blockDim.x + threadIdx.x;
    if (idx >= n * FIN) return;
    int node = idx / FIN, f = idx - node * FIN;
    float v = x[idx];
    int c1 = cl1[node], c2 = cl2[node];
    atomicAdd(&xp1[c1 * FIN + f], v);
    atomicAdd(&xp2[c2 * FIN + f], v);
    if (f == 0) { atomicAdd(&cnt1[c1], 1.f); atomicAdd(&cnt2[c2], 1.f); }
}

__global__ void k_divcnt(float* xp, const float* __restrict__ cnt, int c) {
    int idx = blockIdx.x * blockDim.x + threadIdx.x;
    if (idx >= c * FIN) return;
    xp[idx] = xp[idx] / fmaxf(cnt[idx / FIN], 1.f);
}

// fused mix: thread per node; BN+ReLU for all three branches via precomputed
// scale/shift (uniform scalar loads); Wm/bm scalar-indexed.
__global__ void k_final(const float* __restrict__ acc1, const float* __restrict__ sc1,
                        const float* __restrict__ h2, const float* __restrict__ sc2,
                        const int* __restrict__ cl1,
                        const float* __restrict__ h3, const float* __restrict__ sc3,
                        const int* __restrict__ cl2,
                        const float* __restrict__ x, const float* __restrict__ Wm,
                        const float* __restrict__ bm, float* __restrict__ out, int n) {
    int t = blockIdx.x * blockDim.x + threadIdx.x;
    if (t >= n) return;
    float o[NOUT];
#pragma unroll
    for (int j = 0; j < NOUT; ++j) o[j] = bm[j];
    {
        const float4* r4 = reinterpret_cast<const float4*>(acc1 + (size_t)t * NHID);
#pragma unroll
        for (int i4 = 0; i4 < NHID / 4; ++i4) {
            float4 v = r4[i4];
            float hv[4] = {v.x, v.y, v.z, v.w};
#pragma unroll
            for (int c = 0; c < 4; ++c) {
                int i = i4 * 4 + c;
                float h = fmaxf(fmaf(hv[c], sc1[i], sc1[NHID + i]), 0.f);
#pragma unroll
                for (int j = 0; j < NOUT; ++j) o[j] = fmaf(h, Wm[i * NOUT + j], o[j]);
            }
        }
    }
    {
        const float4* r4 = reinterpret_cast<const float4*>(h2 + (size_t)cl1[t] * NHID);
#pragma unroll
        for (int i4 = 0; i4 < NHID / 4; ++i4) {
            float4 v = r4[i4];
            float hv[4] = {v.x, v.y, v.z, v.w};
#pragma unroll
            for (int c = 0; c < 4; ++c) {
                int hid = i4 * 4 + c;
                float h = fmaxf(fmaf(hv[c], sc2[hid], sc2[NHID + hid]), 0.f);
#pragma unroll
                for (int j = 0; j < NOUT; ++j) o[j] = fmaf(h, Wm[(NHID + hid) * NOUT + j], o[j]);
            }
        }
    }
    {
        const float4* r4 = reinterpret_cast<const float4*>(h3 + (size_t)cl2[t] * NHID);
#pragma unroll
        for (int i4 = 0; i4 < NHID / 4; ++i4) {
            float4 v = r4[i4];
            float hv[4] = {v.x, v.y, v.z, v.w};
#pragma unroll
            for (int c = 0; c < 4; ++c) {
                int hid = i4 * 4 + c;
                float h = fmaxf(fmaf(hv[c], sc3[hid], sc3[NHID + hid]), 0.f);
#pragma unroll
                for (int j = 0; j < NOUT; ++j) o[j] = fmaf(h, Wm[(2 * NHID + hid) * NOUT + j], o[j]);
            }
        }
    }
    {
        const float4* r4 = reinterpret_cast<const float4*>(x + (size_t)t * FIN);
#pragma unroll
        for (int i4 = 0; i4 < FIN / 4; ++i4) {
            float4 v = r4[i4];
            float hv[4] = {v.x, v.y, v.z, v.w};
#pragma unroll
            for (int c = 0; c < 4; ++c) {
                int i = 3 * NHID + i4 * 4 + c;
#pragma unroll
                for (int j = 0; j < NOUT; ++j) o[j] = fmaf(hv[c], Wm[i * NOUT + j], o[j]);
            }
        }
    }
    float* op = out + (size_t)t * NOUT;
#pragma unroll
    for (int j = 0; j < NOUT; ++j) op[j] = o[j];
}

extern "C" void kernel_launch(void* const* d_in, const int* in_sizes, int n_in,
                              void* d_out, int out_size, void* d_ws, size_t ws_size,
                              hipStream_t stream) {
    const int N = 200000, E = 800000;
    const int C1n = 20000, E1 = 80000;
    const int C2n = 2000, E2 = 8000;

    const float* x  = (const float*)d_in[0];
    const int* ei   = (const int*)d_in[1];
    const int* cl1  = (const int*)d_in[2];
    const int* cl2  = (const int*)d_in[3];
    const int* eic1 = (const int*)d_in[4];
    const int* eic2 = (const int*)d_in[5];
    const float* W1 = (const float*)d_in[6];  const float* b1 = (const float*)d_in[7];
    const float* g1 = (const float*)d_in[8];  const float* bt1 = (const float*)d_in[9];
    const float* W2 = (const float*)d_in[10]; const float* b2 = (const float*)d_in[11];
    const float* g2 = (const float*)d_in[12]; const float* bt2 = (const float*)d_in[13];
    const float* W3 = (const float*)d_in[14]; const float* b3 = (const float*)d_in[15];
    const float* g3 = (const float*)d_in[16]; const float* bt3 = (const float*)d_in[17];
    const float* Wm = (const float*)d_in[18]; const float* bm = (const float*)d_in[19];

    char* wb = (char*)d_ws;
    size_t off = 0;
    auto alloc = [&](size_t nwords) {
        void* p = wb + off; off += ((nwords + 3) & ~(size_t)3) * 4; return p;
    };
    // --- zero-region ---
    int* degi1 = (int*)alloc(N);   int* fill1 = (int*)alloc(N);
    int* degi2 = (int*)alloc(C1n); int* fill2 = (int*)alloc(C1n);
    int* degi3 = (int*)alloc(C2n); int* fill3 = (int*)alloc(C2n);
    float* st1 = (float*)alloc(128); float* st2 = (float*)alloc(128); float* st3 = (float*)alloc(128);
    float* xp1 = (float*)alloc((size_t)C1n * FIN); float* cnt1 = (float*)alloc(C1n);
    float* xp2 = (float*)alloc((size_t)C2n * FIN); float* cnt2 = (float*)alloc(C2n);
    size_t zero_bytes = off;
    // --- fully-overwritten region ---
    int* rp1 = (int*)alloc(N + 1);   int2* cv1 = (int2*)alloc(2 * (size_t)E);
    int* rp2 = (int*)alloc(C1n + 1); int2* cv2 = (int2*)alloc(2 * (size_t)E1);
    int* rp3 = (int*)alloc(C2n + 1); int2* cv3 = (int2*)alloc(2 * (size_t)E2);
    float* dis1 = (float*)alloc(N); float* dis2 = (float*)alloc(C1n); float* dis3 = (float*)alloc(C2n);
    int* bsum = (int*)alloc(1024);
    float* scsh1 = (float*)alloc(128); float* scsh2 = (float*)alloc(128); float* scsh3 = (float*)alloc(128);
    float* Wt1 = (float*)alloc(9216); float* Wt2 = (float*)alloc(9216); float* Wt3 = (float*)alloc(9216);
    float* T1[5]; for (int i = 0; i < 5; ++i) T1[i] = (float*)alloc((size_t)N * FIN);
    float* T2[5]; for (int i = 0; i < 5; ++i) T2[i] = (float*)alloc((size_t)C1n * FIN);
    float* T3[5]; for (int i = 0; i < 5; ++i) T3[i] = (float*)alloc((size_t)C2n * FIN);
    float* acc1 = (float*)alloc((size_t)N * NHID);
    float* acc2 = (float*)alloc((size_t)C1n * NHID);
    float* acc3 = (float*)alloc((size_t)C2n * NHID);
    if (off > ws_size) return;  // fail visibly if ws too small

    (void)hipMemsetAsync(d_ws, 0, zero_bytes, stream);

    const int T = 256;
    auto cdiv = [](int a, int b) { return (a + b - 1) / b; };

    // transpose all Cheb weights up front (independent of everything else)
    k_wt3<<<cdiv(3 * 9216, T), T, 0, stream>>>(W1, Wt1, W2, Wt2, W3, Wt3);

    auto branch = [&](const float* xin, int n, const int* e, int Ecnt,
                      const float* Wt, const float* bb, int* degi, int* fill, float* dis,
                      int* rp, int2* cv, float** Tb, float* acc, float* st) {
        int ge = cdiv(Ecnt, T);
        int nb = cdiv(n + 1, 256);
        int ntiles = cdiv(n, 256);
        int gg = cdiv(ntiles, 8) * 32;  // gemv6: XCD-remapped (tile x 4 chunks)
        int gp = cdiv(n * 6, T);        // propg: thread per (node, chunk)
        // CSR build
        k_hist<<<ge, T, 0, stream>>>(e, Ecnt, degi);
        k_scan_local<<<nb, 256, 0, stream>>>(degi, n, rp, bsum, dis);
        k_scan_bsum<<<1, 256, 0, stream>>>(bsum, nb);
        k_scan_add<<<nb, 256, 0, stream>>>(rp, bsum, n);
        k_fill<<<ge, T, 0, stream>>>(e, Ecnt, dis, rp, fill, cv);
        // Chebyshev chain: Tb[0]=Tx1 .. Tb[4]=Tx5
        k_propg<<<gp, T, 0, stream>>>(rp, cv, 1.0f, xin, nullptr, Tb[0], n);
        k_propg<<<gp, T, 0, stream>>>(rp, cv, 2.0f, Tb[0], xin, Tb[1], n);
        k_propg<<<gp, T, 0, stream>>>(rp, cv, 2.0f, Tb[1], Tb[0], Tb[2], n);
        k_propg<<<gp, T, 0, stream>>>(rp, cv, 2.0f, Tb[2], Tb[1], Tb[3], n);
        k_propg<<<gp, T, 0, stream>>>(rp, cv, 2.0f, Tb[3], Tb[2], Tb[4], n);
        // single-pass 6-term gemv (+BN stats)
        k_gemv6<<<gg, T, 0, stream>>>(xin, Tb[0], Tb[1], Tb[2], Tb[3], Tb[4],
                                      Wt, bb, acc, st, n);
    };

    // branch 1: full graph
    branch(x, N, ei, E, Wt1, b1, degi1, fill1, dis1, rp1, cv1, T1, acc1, st1);
    // pooled inputs for branches 2 & 3 (single pass over x)
    k_scatter2<<<cdiv(N * FIN, T), T, 0, stream>>>(x, cl1, cl2, N, xp1, cnt1, xp2, cnt2);
    k_divcnt<<<cdiv(C1n * FIN, T), T, 0, stream>>>(xp1, cnt1, C1n);
    branch(xp1, C1n, eic1, E1, Wt2, b2, degi2, fill2, dis2, rp2, cv2, T2, acc2, st2);
    k_divcnt<<<cdiv(C2n * FIN, T), T, 0, stream>>>(xp2, cnt2, C2n);
    branch(xp2, C2n, eic2, E2, Wt3, b3, degi3, fill3, dis3, rp3, cv3, T3, acc3, st3);
    // BN coefficients for all three branches, then fused final mix
    k_bnprep3<<<1, 192, 0, stream>>>(st1, g1, bt1, 1.0f / (float)N,
                                     st2, g2, bt2, 1.0f / (float)C1n,
                                     st3, g3, bt3, 1.0f / (float)C2n,
                                     scsh1, scsh2, scsh3);
    k_final<<<cdiv(N, T), T, 0, stream>>>(acc1, scsh1, acc2, scsh2, cl1,
                                          acc3, scsh3, cl2,
                                          x, Wm, bm, (float*)d_out, N);
}